// Round 3
// baseline (182.176 us; speedup 1.0000x reference)
//
#include <hip/hip_runtime.h>

#define WW 320          // input width/height
#define OWID 314        // output cols
#define OHEI 314        // output rows
#define BB 64           // batch
#define RPB 8           // output rows per band
#define NBAND 40        // ceil(314/8)
#define NSTRIP 79       // ceil(314/4) output-col strips of 4
#define NTH 256
#define NBLK ((BB * NBAND * NSTRIP) / NTH)   // 64*40*79/256 = 790 exactly

// Compute the 4 horizontal 7-tap sums of the 5 channel-combined moments for
// one input row. h[q*4+j] for moment q in {sx,sy,sxx,syy,sxy}, output col j.
__device__ __forceinline__ void compute_h(
    const float* __restrict__ X0, const float* __restrict__ X1,
    const float* __restrict__ Y0, const float* __restrict__ Y1,
    int off, int o2, float h[20])
{
    float4 ax0 = *(const float4*)(X0 + off);
    float4 ax1 = *(const float4*)(X0 + off + 4);
    float4 ax2 = *(const float4*)(X0 + off + o2);
    float4 bx0 = *(const float4*)(X1 + off);
    float4 bx1 = *(const float4*)(X1 + off + 4);
    float4 bx2 = *(const float4*)(X1 + off + o2);
    float4 ay0 = *(const float4*)(Y0 + off);
    float4 ay1 = *(const float4*)(Y0 + off + 4);
    float4 ay2 = *(const float4*)(Y0 + off + o2);
    float4 by0 = *(const float4*)(Y1 + off);
    float4 by1 = *(const float4*)(Y1 + off + 4);
    float4 by2 = *(const float4*)(Y1 + off + o2);

    float x0[10] = {ax0.x, ax0.y, ax0.z, ax0.w, ax1.x, ax1.y, ax1.z, ax1.w, ax2.x, ax2.y};
    float x1[10] = {bx0.x, bx0.y, bx0.z, bx0.w, bx1.x, bx1.y, bx1.z, bx1.w, bx2.x, bx2.y};
    float y0[10] = {ay0.x, ay0.y, ay0.z, ay0.w, ay1.x, ay1.y, ay1.z, ay1.w, ay2.x, ay2.y};
    float y1[10] = {by0.x, by0.y, by0.z, by0.w, by1.x, by1.y, by1.z, by1.w, by2.x, by2.y};

    float sx[10], sy[10], sxx[10], syy[10], sxy[10];
    #pragma unroll
    for (int j = 0; j < 10; ++j) {
        sx[j]  = x0[j] + x1[j];
        sy[j]  = y0[j] + y1[j];
        sxx[j] = x0[j] * x0[j] + x1[j] * x1[j];
        syy[j] = y0[j] * y0[j] + y1[j] * y1[j];
        sxy[j] = x0[j] * y0[j] + x1[j] * y1[j];
    }
    #pragma unroll
    for (int q = 0; q < 5; ++q) {
        const float* m = (q == 0) ? sx : (q == 1) ? sy : (q == 2) ? sxx : (q == 3) ? syy : sxy;
        float t0 = ((m[0] + m[1]) + (m[2] + m[3])) + ((m[4] + m[5]) + m[6]);
        float t1 = t0 - m[0] + m[7];
        float t2 = t1 - m[1] + m[8];
        float t3 = t2 - m[2] + m[9];
        h[q * 4 + 0] = t0; h[q * 4 + 1] = t1; h[q * 4 + 2] = t2; h[q * 4 + 3] = t3;
    }
}

__global__ __launch_bounds__(NTH) void ssim_main(
    const float* __restrict__ X, const float* __restrict__ Y,
    const float* __restrict__ dr, double* __restrict__ acc,
    unsigned* __restrict__ counter, float* __restrict__ out)
{
    const int wi   = blockIdx.x * NTH + threadIdx.x;   // grid sized exactly
    const int s    = wi % NSTRIP;
    const int g    = wi / NSTRIP;
    const int band = g % NBAND;
    const int b    = g / NBAND;
    const int r0   = band * RPB;
    const int r1   = min(r0 + RPB, OHEI);
    const int cb   = s * 4;
    const int o2   = (cb <= 308) ? 8 : 4;   // clamp 3rd float4 for last strip

    const size_t plane = (size_t)WW * WW;
    const float* X0 = X + (size_t)b * 2 * plane;
    const float* X1 = X0 + plane;
    const float* Y0 = Y + (size_t)b * 2 * plane;
    const float* Y1 = Y0 + plane;

    // SSIM constants folded to raw-window-sum form (x49^2):
    //   C1p = 49^2 * (K1*d)^2, C2p = 49^2 * (K2*d)^2, cn = 49/48
    const float d   = dr[b];
    const float C1p = 2401.0f * (0.01f * d) * (0.01f * d);
    const float C2p = 2401.0f * (0.03f * d) * (0.03f * d);
    const float cn  = 49.0f / 48.0f;

    float cm[4];
    #pragma unroll
    for (int j = 0; j < 4; ++j) cm[j] = (cb + j < OWID) ? 1.0f : 0.0f;

    float v[20];
    #pragma unroll
    for (int i = 0; i < 20; ++i) v[i] = 0.0f;

    // warm-up: rows r0 .. r0+5
    for (int k = 0; k < 6; ++k) {
        float h[20];
        compute_h(X0, X1, Y0, Y1, (r0 + k) * WW + cb, o2, h);
        #pragma unroll
        for (int i = 0; i < 20; ++i) v[i] += h[i];
    }

    float ssum = 0.0f;
    for (int t = r0; t < r1; ++t) {
        float hn[20];
        compute_h(X0, X1, Y0, Y1, (t + 6) * WW + cb, o2, hn);
        #pragma unroll
        for (int i = 0; i < 20; ++i) v[i] += hn[i];

        // SSIM from raw window sums V (all /49 and /2401 factors cancel)
        #pragma unroll
        for (int j = 0; j < 4; ++j) {
            const float V0 = v[j],      V1 = v[4 + j];
            const float V2 = v[8 + j],  V3 = v[12 + j], V4 = v[16 + j];
            const float t01 = V0 * V1;
            const float t00 = V0 * V0;
            const float t11 = V1 * V1;
            const float A1  = 2.0f * t01 + C1p;
            const float A2  = fmaf(2.0f * cn, fmaf(49.0f, V4, -t01), C2p);
            const float B1  = t00 + t11 + C1p;
            const float p0  = fmaf(49.0f, V2, -t00);
            const float p1  = fmaf(49.0f, V3, -t11);
            const float B2  = fmaf(cn, p0 + p1, C2p);
            ssum = fmaf(cm[j], (A1 * A2) * __builtin_amdgcn_rcpf(B1 * B2), ssum);
        }

        float ho[20];
        compute_h(X0, X1, Y0, Y1, t * WW + cb, o2, ho);
        #pragma unroll
        for (int i = 0; i < 20; ++i) v[i] -= ho[i];
    }

    // ---- reduction: wave shuffle (double) -> LDS -> one atomic per block ----
    double local = (double)ssum;
    #pragma unroll
    for (int off = 32; off > 0; off >>= 1)
        local += __shfl_down(local, off, 64);
    __shared__ double wsum[NTH / 64];
    const int lane = threadIdx.x & 63, wid = threadIdx.x >> 6;
    if (lane == 0) wsum[wid] = local;
    __syncthreads();
    if (threadIdx.x == 0) {
        double tot = (wsum[0] + wsum[1]) + (wsum[2] + wsum[3]);
        atomicAdd(acc, tot);
        __threadfence();
        unsigned ticket = atomicAdd(counter, 1u);
        if (ticket == NBLK - 1) {
            double stot = atomicAdd(acc, 0.0);   // device-scope coherent read
            const double N = (double)BB * (double)OHEI * (double)OWID;
            out[0] = (float)(1.0 - stot / N);
        }
    }
}

extern "C" void kernel_launch(void* const* d_in, const int* in_sizes, int n_in,
                              void* d_out, int out_size, void* d_ws, size_t ws_size,
                              hipStream_t stream)
{
    const float* X  = (const float*)d_in[0];
    const float* Y  = (const float*)d_in[1];
    const float* dr = (const float*)d_in[2];
    // d_in[3] is the box kernel w (all 1/49) — folded into constants.
    double*   acc     = (double*)d_ws;
    unsigned* counter = (unsigned*)((char*)d_ws + 8);
    float*    out     = (float*)d_out;

    hipMemsetAsync(d_ws, 0, 16, stream);
    ssim_main<<<dim3(NBLK), dim3(NTH), 0, stream>>>(X, Y, dr, acc, counter, out);
}